// Round 12
// baseline (181.744 us; speedup 1.0000x reference)
//
#include <hip/hip_runtime.h>

typedef unsigned short u16;
typedef unsigned int u32;
typedef __attribute__((ext_vector_type(4))) float f32x4;
typedef __attribute__((ext_vector_type(8))) short s16x8;
typedef __attribute__((ext_vector_type(4))) short s16x4;

static constexpr int N_ = 4096;
static constexpr int D_ = 1024;

#define MEMCLOB() asm volatile("" ::: "memory")

__device__ __forceinline__ u16 f2bf(float f) {
  unsigned u = __float_as_uint(f);
  u += 0x7FFFu + ((u >> 16) & 1u);  // RNE
  return (u16)(u >> 16);
}
__device__ __forceinline__ float bf2f(u16 v) {
  return __uint_as_float((u32)v << 16);
}
__device__ __forceinline__ f32x4 zero4() {
  f32x4 z; z[0] = 0.f; z[1] = 0.f; z[2] = 0.f; z[3] = 0.f; return z;
}

// ---------------- K0: prep WpB bf16 + M = Pow @ Wsum ----------------
__global__ __launch_bounds__(256) void k_aux(
    const float* __restrict__ Wpm, const float* __restrict__ piw,
    const float* __restrict__ pw, u16* __restrict__ WpB,
    u16* __restrict__ MB) {
  __shared__ float Ws[64][65];
  int bid = blockIdx.x, tid = threadIdx.x;
  if (bid < 16) {
    size_t i0 = (size_t)bid * 4096;
    for (int idx = tid; idx < 4096; idx += 256)
      WpB[i0 + idx] = f2bf(piw[i0 + idx]);
    return;
  }
  int idx2 = bid - 16;
  int b = idx2 >> 4, t = idx2 & 15;
  for (int idx = tid; idx < 4096; idx += 256) {
    float s = 0.f;
#pragma unroll
    for (int k = 0; k < 8; ++k)
      s += Wpm[((size_t)(b * 8 + k)) * 4096 + idx];
    Ws[idx >> 6][idx & 63] = s;
  }
  __syncthreads();
  u16* mb = MB + ((size_t)b << 16);
  for (int oidx = tid; oidx < 4096; oidx += 256) {
    int r = oidx >> 6, c = oidx & 63;
    int drow = t * 64 + r;
    const float* prow = pw + (size_t)drow * 64;
    float acc = 0.f;
#pragma unroll 8
    for (int q = 0; q < 64; ++q) acc += prow[q] * Ws[q][c];
    mb[(size_t)drow * 64 + c] = f2bf(acc);
  }
}

// ---------------- K1: Sur norms + pre K-quarter partials ----------------
// 2048 blocks (8 b x 256 tiles of 16 rows), 256 threads (4 waves).
// Wave w computes K-quarter [w*256, w*256+256) of pre for the 16 rows.
// Barrier-free; per-thread flat load batches keep ~16 KB/wave in flight.
__global__ __launch_bounds__(256, 4) void k1(
    const float* __restrict__ H, const float* __restrict__ Sur,
    const float* __restrict__ sscale_p, const float* __restrict__ sbias_p,
    const u16* __restrict__ WpB, u16* __restrict__ preQ,
    float* __restrict__ sqs_ws) {
  const int tid = threadIdx.x;
  const int lane = tid & 63;
  const int w = tid >> 6;
  const int llo = lane & 15;
  const int lhi = lane >> 4;
  const int b = blockIdx.x >> 8;
  const int row0 = (blockIdx.x & 255) * 16;

  // ---- Sur row norms: 16 threads/row, 16 upfront float4 loads each ----
  {
    const float* sp =
        Sur + ((size_t)b * N_ + row0 + (tid >> 4)) * D_ + (tid & 15) * 4;
    float4 sv[16];
#pragma unroll
    for (int i = 0; i < 16; ++i) sv[i] = *(const float4*)(sp + i * 64);
    MEMCLOB();
    float a = 0.f;
#pragma unroll
    for (int i = 0; i < 16; ++i)
      a += sv[i].x * sv[i].x + sv[i].y * sv[i].y + sv[i].z * sv[i].z +
           sv[i].w * sv[i].w;
    a += __shfl_xor(a, 1, 64);
    a += __shfl_xor(a, 2, 64);
    a += __shfl_xor(a, 4, 64);
    a += __shfl_xor(a, 8, 64);
    if ((tid & 15) == 0) {
      float mag = sqrtf(a);
      float s = 1.f / (1.f + __expf(-(sscale_p[0] * mag + sbias_p[0])));
      sqs_ws[b * N_ + row0 + (tid >> 4)] = sqrtf(s);
    }
  }

  // ---- GEMM quarter: 16 upfront H loads, then 8 chunks of MFMA ----
  const float* hrow =
      H + ((size_t)b * N_ + row0 + llo) * D_ + w * 256 + lhi * 8;
  float4 ah[16];
#pragma unroll
  for (int c = 0; c < 8; ++c) {
    ah[2 * c] = *(const float4*)(hrow + c * 32);
    ah[2 * c + 1] = *(const float4*)(hrow + c * 32 + 4);
  }
  MEMCLOB();
  f32x4 acc[4];
#pragma unroll
  for (int t = 0; t < 4; ++t) acc[t] = zero4();
  const u16* wpb = WpB + w * 256 + lhi * 8;
#pragma unroll
  for (int c = 0; c < 8; ++c) {
    s16x8 af;
    af[0] = (short)f2bf(ah[2 * c].x); af[1] = (short)f2bf(ah[2 * c].y);
    af[2] = (short)f2bf(ah[2 * c].z); af[3] = (short)f2bf(ah[2 * c].w);
    af[4] = (short)f2bf(ah[2 * c + 1].x); af[5] = (short)f2bf(ah[2 * c + 1].y);
    af[6] = (short)f2bf(ah[2 * c + 1].z); af[7] = (short)f2bf(ah[2 * c + 1].w);
#pragma unroll
    for (int t = 0; t < 4; ++t) {
      s16x8 bs = *(const s16x8*)(wpb + (size_t)(t * 16 + llo) * 1024 + c * 32);
      // swapped operands: acc[t][r] = pre[row=llo][p = t*16 + lhi*4 + r]
      acc[t] = __builtin_amdgcn_mfma_f32_16x16x32_bf16(bs, af, acc[t], 0, 0, 0);
    }
  }
  // write bf16 quarter-partials: 4 consecutive p per lane -> 8-B stores
  u16* pq = preQ + ((size_t)w << 21) + ((size_t)(b * N_ + row0 + llo)) * 64;
#pragma unroll
  for (int t = 0; t < 4; ++t) {
    s16x4 v;
#pragma unroll
    for (int r = 0; r < 4; ++r) v[r] = (short)f2bf(acc[t][r]);
    *(s16x4*)(pq + t * 16 + lhi * 4) = v;
  }
}

// ---------------- K2: combine quarters + G + pm_read ----------------
// 512 blocks (8 b x 64 tiles of 64 rows), 512 threads (8 waves).
// wave w: wm=w&3 (16-row tile), wk=w>>2 (k-half in G / N-half in D).
__global__ __launch_bounds__(512, 4) void k23(
    const u16* __restrict__ preQ, const float* __restrict__ pib,
    const float* __restrict__ pob, const u16* __restrict__ MB,
    const float* __restrict__ sqs_ws, u16* __restrict__ GpartB,
    float* __restrict__ out) {
  __shared__ __align__(16) u16 preRP[64 * 80];  // [row][p], stride 80
  __shared__ __align__(16) u16 wRPT[64 * 80];   // [p][row], stride 80
  const int tid = threadIdx.x;
  const int lane = tid & 63;
  const int w = tid >> 6;
  const int wm = w & 3;
  const int wk = w >> 2;
  const int llo = lane & 15;
  const int lhi = lane >> 4;
  const int b = blockIdx.x >> 6;
  const int row0 = (blockIdx.x & 63) * 64;

  // ---- combine: each thread does one row x 8 cols ----
  {
    const int row = tid >> 3, col0 = (tid & 7) * 8;
    const u16* pq = preQ + ((size_t)(b * N_ + row0 + row)) * 64 + col0;
    float sum[8] = {0, 0, 0, 0, 0, 0, 0, 0};
#pragma unroll
    for (int q = 0; q < 4; ++q) {
      s16x8 v = *(const s16x8*)(pq + (size_t)q * 2097152);
#pragma unroll
      for (int j = 0; j < 8; ++j) sum[j] += bf2f((u16)v[j]);
    }
    float4 bb0 = *(const float4*)&pib[col0];
    float4 bb1 = *(const float4*)&pib[col0 + 4];
    sum[0] += bb0.x; sum[1] += bb0.y; sum[2] += bb0.z; sum[3] += bb0.w;
    sum[4] += bb1.x; sum[5] += bb1.y; sum[6] += bb1.z; sum[7] += bb1.w;
    float sq = sqs_ws[b * N_ + row0 + row];
    s16x8 pr;
#pragma unroll
    for (int j = 0; j < 8; ++j) pr[j] = (short)f2bf(sum[j]);
    *(s16x8*)&preRP[row * 80 + col0] = pr;
#pragma unroll
    for (int j = 0; j < 8; ++j)
      wRPT[(col0 + j) * 80 + row] = f2bf(sum[j] * sq);
  }
  __syncthreads();

  // ---- G: per-block partial (wk selects 32-row half) ----
  {
    s16x8 ag = *(const s16x8*)&wRPT[(wm * 16 + llo) * 80 + wk * 32 + lhi * 8];
    f32x4 accG[4];
#pragma unroll
    for (int t = 0; t < 4; ++t) {
      s16x8 bg = *(const s16x8*)&wRPT[(t * 16 + llo) * 80 + wk * 32 + lhi * 8];
      accG[t] = __builtin_amdgcn_mfma_f32_16x16x32_bf16(ag, bg, zero4(), 0, 0, 0);
    }
    u16* gout = GpartB + ((size_t)blockIdx.x * 2 + wk) * 4096;
#pragma unroll
    for (int t = 0; t < 4; ++t)
#pragma unroll
      for (int r = 0; r < 4; ++r)
        gout[(wm * 16 + lhi * 4 + r) * 64 + t * 16 + llo] = f2bf(accG[t][r]);
  }

  // ---- phase D: pm_read = pre @ M^T + bias (swapped, float4 stores) ----
  {
    s16x8 ad0 = *(const s16x8*)&preRP[(wm * 16 + llo) * 80 + lhi * 8];
    s16x8 ad1 = *(const s16x8*)&preRP[(wm * 16 + llo) * 80 + 32 + lhi * 8];
    const u16* mcol = MB + ((size_t)b << 16) + (size_t)(wk * 512) * 64 + lhi * 8;
    float* orow = out + ((size_t)b * N_ + row0 + wm * 16 + llo) * D_ + wk * 512;
    const float* pobw = pob + wk * 512;
#pragma unroll
    for (int c = 0; c < 8; ++c) {
      s16x8 f0[4], f1[4];
#pragma unroll
      for (int i = 0; i < 4; ++i) {
        const u16* p = mcol + (size_t)(c * 64 + i * 16 + llo) * 64;
        f0[i] = *(const s16x8*)p;
        f1[i] = *(const s16x8*)(p + 32);
      }
#pragma unroll
      for (int i = 0; i < 4; ++i) {
        f32x4 acc = zero4();
        acc = __builtin_amdgcn_mfma_f32_16x16x32_bf16(f0[i], ad0, acc, 0, 0, 0);
        acc = __builtin_amdgcn_mfma_f32_16x16x32_bf16(f1[i], ad1, acc, 0, 0, 0);
        int n0 = c * 64 + i * 16 + lhi * 4;
        float4 bias4 = *(const float4*)&pobw[n0];
        float4 o;
        o.x = acc[0] + bias4.x;
        o.y = acc[1] + bias4.y;
        o.z = acc[2] + bias4.z;
        o.w = acc[3] + bias4.w;
        *(float4*)(orow + n0) = o;
      }
    }
  }
}

// ---------------- K3: reduce GpartB (bf16) -> Gsum (f32) ----------------
__global__ __launch_bounds__(256) void k_gred(
    const u16* __restrict__ GpartB, float* __restrict__ Gsum) {
  __shared__ float red[4][64];
  int b = blockIdx.x >> 6, g = blockIdx.x & 63;
  int lane = threadIdx.x & 63, q = threadIdx.x >> 6;
  const u16* src = GpartB + ((size_t)(b * 128 + q * 32)) * 4096 + g * 64 + lane;
  float s = 0.f;
#pragma unroll 8
  for (int i = 0; i < 32; ++i) s += bf2f(src[(size_t)i * 4096]);
  red[q][lane] = s;
  __syncthreads();
  if (q == 0)
    Gsum[(size_t)b * 4096 + g * 64 + lane] =
        red[0][lane] + red[1][lane] + red[2][lane] + red[3][lane];
}

// ---------------- K4: W_new = W_pm @ (decay*I + beta*G/N), frob clip ----------------
__global__ __launch_bounds__(256) void k_wnew(
    const float* __restrict__ Wpm, const float* __restrict__ Gsum,
    const float* __restrict__ rbeta, const float* __restrict__ rdecay,
    float* __restrict__ outW) {
  __shared__ float Wk[64][66];
  __shared__ float Gl[64][66];
  __shared__ float red[4];
  int bk = blockIdx.x;
  int b = bk >> 3, k = bk & 7;
  int tid = threadIdx.x;
  const float* wsrc = Wpm + (size_t)bk * 4096;
  const float* gsrc = Gsum + (size_t)b * 4096;
  for (int idx = tid; idx < 4096; idx += 256) {
    Wk[idx >> 6][idx & 63] = wsrc[idx];
    Gl[idx >> 6][idx & 63] = gsrc[idx];
  }
  __syncthreads();
  float beta = log1pf(__expf(rbeta[k]));
  float decay = 1.f / (1.f + __expf(-rdecay[k]));
  float bn = beta * (1.f / 4096.f);  // G partials are unnormalized
  int q = tid & 63;
  int rbase = tid >> 6;
  float vals[16];
  float ss = 0.f;
#pragma unroll
  for (int i = 0; i < 16; ++i) {
    int row = i * 4 + rbase;
    float acc = 0.f;
#pragma unroll 8
    for (int j = 0; j < 64; ++j) acc += Wk[row][j] * Gl[j][q];
    float v = decay * Wk[row][q] + bn * acc;
    vals[i] = v;
    ss += v * v;
  }
#pragma unroll
  for (int m = 1; m < 64; m <<= 1) ss += __shfl_xor(ss, m, 64);
  if ((tid & 63) == 0) red[tid >> 6] = ss;
  __syncthreads();
  float frob = sqrtf(red[0] + red[1] + red[2] + red[3]);
  float scale = fminf(16.f / fmaxf(frob, 1e-8f), 1.f);
  float* dst = outW + (size_t)bk * 4096;
#pragma unroll
  for (int i = 0; i < 16; ++i) dst[i * 256 + tid] = vals[i] * scale;
}

extern "C" void kernel_launch(void* const* d_in, const int* in_sizes, int n_in,
                              void* d_out, int out_size, void* d_ws, size_t ws_size,
                              hipStream_t stream) {
  const float* H      = (const float*)d_in[0];
  const float* Sur    = (const float*)d_in[1];
  const float* Wpm    = (const float*)d_in[2];
  const float* piw    = (const float*)d_in[3];
  const float* pib    = (const float*)d_in[4];
  const float* pw     = (const float*)d_in[5];
  const float* pob    = (const float*)d_in[6];
  const float* rbeta  = (const float*)d_in[7];
  const float* rdecay = (const float*)d_in[8];
  const float* sscale = (const float*)d_in[9];
  const float* sbias  = (const float*)d_in[10];
  float* out = (float*)d_out;

  char* ws = (char*)d_ws;
  u16* WpB      = (u16*)(ws);               // [64][1024] bf16      = 131072 B
  u16* MB       = (u16*)(ws + 131072);      // [8][1024][64] bf16   = 1 MB
  float* sqs_ws = (float*)(ws + 1179648);   // [8][4096] f32        = 131072 B
  float* Gsum   = (float*)(ws + 1310720);   // [8][64][64] f32      = 131072 B
  u16* GpartB   = (u16*)(ws + 1441792);     // [1024][64][64] bf16  = 8 MB
  u16* preQ     = (u16*)(ws + 9830400);     // [4][32768][64] bf16  = 16 MB

  k_aux<<<144, 256, 0, stream>>>(Wpm, piw, pw, WpB, MB);
  k1<<<2048, 256, 0, stream>>>(H, Sur, sscale, sbias, WpB, preQ, sqs_ws);
  k23<<<512, 512, 0, stream>>>(preQ, pib, pob, MB, sqs_ws, GpartB, out);
  k_gred<<<512, 256, 0, stream>>>(GpartB, Gsum);
  k_wnew<<<64, 256, 0, stream>>>(Wpm, Gsum, rbeta, rdecay,
                                 out + (size_t)8 * 4096 * 1024);
}

// Round 13
// 138.569 us; speedup vs baseline: 1.3116x; 1.3116x over previous
//
#include <hip/hip_runtime.h>

typedef unsigned short u16;
typedef unsigned int u32;
typedef __attribute__((ext_vector_type(4))) float f32x4;
typedef __attribute__((ext_vector_type(8))) short s16x8;

static constexpr int N_ = 4096;
static constexpr int D_ = 1024;

#define WAITV(N) asm volatile("s_waitcnt vmcnt(" #N ")" ::: "memory")
#define MEMCLOB() asm volatile("" ::: "memory")

__device__ __forceinline__ u16 f2bf(float f) {
  unsigned u = __float_as_uint(f);
  u += 0x7FFFu + ((u >> 16) & 1u);  // RNE
  return (u16)(u >> 16);
}
__device__ __forceinline__ f32x4 zero4() {
  f32x4 z; z[0] = 0.f; z[1] = 0.f; z[2] = 0.f; z[3] = 0.f; return z;
}
__device__ __forceinline__ void gload16(const void* g, void* lds) {
  __builtin_amdgcn_global_load_lds(
      (const __attribute__((address_space(1))) u32*)g,
      (__attribute__((address_space(3))) u32*)lds, 16, 0, 0);
}

// ---------------- K0: prep (WpB, MB) + surprise norms ----------------
// blocks 0..15: WpB bf16; 16..143: M = Pow @ Wsum; 144..2191: row norms.
__global__ __launch_bounds__(256) void k_aux(
    const float* __restrict__ Wpm, const float* __restrict__ piw,
    const float* __restrict__ pw, const float* __restrict__ Sur,
    const float* __restrict__ sscale_p, const float* __restrict__ sbias_p,
    u16* __restrict__ WpB, u16* __restrict__ MB, float* __restrict__ sqs_ws) {
  __shared__ float Ws[64][65];
  int bid = blockIdx.x, tid = threadIdx.x;
  if (bid < 16) {
    size_t i0 = (size_t)bid * 4096;
    for (int idx = tid; idx < 4096; idx += 256)
      WpB[i0 + idx] = f2bf(piw[i0 + idx]);
    return;
  }
  if (bid < 144) {
    int idx2 = bid - 16;
    int b = idx2 >> 4, t = idx2 & 15;
    for (int idx = tid; idx < 4096; idx += 256) {
      float s = 0.f;
#pragma unroll
      for (int k = 0; k < 8; ++k)
        s += Wpm[((size_t)(b * 8 + k)) * 4096 + idx];
      Ws[idx >> 6][idx & 63] = s;
    }
    __syncthreads();
    u16* mb = MB + ((size_t)b << 16);
    for (int oidx = tid; oidx < 4096; oidx += 256) {
      int r = oidx >> 6, c = oidx & 63;
      int drow = t * 64 + r;
      const float* prow = pw + (size_t)drow * 64;
      float acc = 0.f;
#pragma unroll 8
      for (int q = 0; q < 64; ++q) acc += prow[q] * Ws[q][c];
      mb[(size_t)drow * 64 + c] = f2bf(acc);
    }
    return;
  }
  // ---- norms: 4 waves, 4 rows each ----
  int w = tid >> 6, lane = tid & 63;
  int fr = (bid - 144) * 16 + w * 4;
  const float4* r0 = (const float4*)(Sur + (size_t)fr * 1024) + lane;
  float s0 = 0.f, s1 = 0.f, s2 = 0.f, s3 = 0.f;
#pragma unroll
  for (int c = 0; c < 4; ++c) {
    float4 v0 = r0[c * 64];
    float4 v1 = r0[256 + c * 64];
    float4 v2 = r0[512 + c * 64];
    float4 v3 = r0[768 + c * 64];
    s0 += v0.x * v0.x + v0.y * v0.y + v0.z * v0.z + v0.w * v0.w;
    s1 += v1.x * v1.x + v1.y * v1.y + v1.z * v1.z + v1.w * v1.w;
    s2 += v2.x * v2.x + v2.y * v2.y + v2.z * v2.z + v2.w * v2.w;
    s3 += v3.x * v3.x + v3.y * v3.y + v3.z * v3.z + v3.w * v3.w;
  }
#pragma unroll
  for (int m = 1; m < 64; m <<= 1) {
    s0 += __shfl_xor(s0, m, 64);
    s1 += __shfl_xor(s1, m, 64);
    s2 += __shfl_xor(s2, m, 64);
    s3 += __shfl_xor(s3, m, 64);
  }
  float res = s0;
  if (lane == 1) res = s1;
  if (lane == 2) res = s2;
  if (lane == 3) res = s3;
  if (lane < 4) {
    float mag = sqrtf(res);
    float s = 1.f / (1.f + __expf(-(sscale_p[0] * mag + sbias_p[0])));
    sqs_ws[fr + lane] = sqrtf(s);
  }
}

// ---------------- K1: fused read/commit main pass (round-4, 81 us) ----------------
// 512 blocks (8 b x 64 tiles), 512 threads (8 waves). wm=w&3 (16 rows),
// wk=w>>2 (K-half in A / k-rows in G / N-half in D).
__global__ __launch_bounds__(512, 4) void k_main(
    const float* __restrict__ H, const float* __restrict__ pib,
    const float* __restrict__ pob, const u16* __restrict__ WpB,
    const u16* __restrict__ MB, const float* __restrict__ sqs_ws,
    float* __restrict__ Gpart, float* __restrict__ out) {
  __shared__ __align__(16) char arena[32768];  // Hs/MBs[2 buf][2 slab][8192] | preF
  __shared__ __align__(16) u16 preRP[64][72];
  __shared__ __align__(16) u16 wRPT[64][72];
  __shared__ float pobL[1024];

  const int tid = threadIdx.x;
  const int lane = tid & 63;
  const int w = tid >> 6;
  const int wm = w & 3;
  const int wk = w >> 2;
  const int llo = lane & 15;
  const int lhi = lane >> 4;
  const int b = blockIdx.x >> 6;
  const int row0 = (blockIdx.x & 63) * 64;

  // small operands into regs early (latency fully hidden)
  float bias_t[4];
#pragma unroll
  for (int t = 0; t < 4; ++t) bias_t[t] = pib[t * 16 + llo];
  float sqs_r[4];
#pragma unroll
  for (int r = 0; r < 4; ++r)
    sqs_r[r] = sqs_ws[b * 4096 + row0 + wm * 16 + lhi * 4 + r];

  // staging lane params (shared by phase A and D)
  const int srow = 8 * w + (lane >> 3);
  const int sc16 = (lane & 7) ^ (srow & 7);

  // ---------------- phase A: pre = H @ Wp^T ----------------
  f32x4 accA[4];
#pragma unroll
  for (int t = 0; t < 4; ++t) accA[t] = zero4();

  const float* hsrc = H + ((size_t)b * N_ + row0 + srow) * D_ + sc16 * 4;
  const u16* wpb = WpB + (size_t)wk * 512 + lhi * 8;

  s16x8 B0[4], B1[4];
  auto LOADB = [&](int kc, s16x8* Bs) {
#pragma unroll
    for (int t = 0; t < 4; ++t)
      Bs[t] = *(const s16x8*)(wpb + (size_t)(t * 16 + llo) * 1024 + kc * 32);
  };
  auto STAGEH = [&](int kc, int buf) {
    gload16(hsrc + kc * 32, arena + buf * 16384 + w * 1024);
    gload16(hsrc + 512 + kc * 32, arena + buf * 16384 + 8192 + w * 1024);
  };
  const int arow = wm * 16 + llo;
  const int r7a = arow & 7;
  auto COMPA = [&](int buf, const s16x8* Bs) {
    const char* abase = arena + buf * 16384 + wk * 8192 + arow * 128;
    f32x4 alo = *(const f32x4*)(abase + (((lhi * 2) ^ r7a) * 16));
    f32x4 ahi = *(const f32x4*)(abase + (((lhi * 2 + 1) ^ r7a) * 16));
    s16x8 af;
    af[0] = (short)f2bf(alo[0]); af[1] = (short)f2bf(alo[1]);
    af[2] = (short)f2bf(alo[2]); af[3] = (short)f2bf(alo[3]);
    af[4] = (short)f2bf(ahi[0]); af[5] = (short)f2bf(ahi[1]);
    af[6] = (short)f2bf(ahi[2]); af[7] = (short)f2bf(ahi[3]);
#pragma unroll
    for (int t = 0; t < 4; ++t)
      accA[t] = __builtin_amdgcn_mfma_f32_16x16x32_bf16(af, Bs[t], accA[t], 0, 0, 0);
  };

  LOADB(0, B0); STAGEH(0, 0);
  MEMCLOB();
  LOADB(1, B1); STAGEH(1, 1);
  MEMCLOB();

  for (int kc = 0; kc < 16; kc += 2) {
    WAITV(6);
    __builtin_amdgcn_s_barrier();
    COMPA(0, B0);
    MEMCLOB();
    __builtin_amdgcn_s_barrier();
    if (kc + 2 < 16) { LOADB(kc + 2, B0); STAGEH(kc + 2, 0); }
    MEMCLOB();
    if (kc + 1 == 15) { WAITV(0); } else { WAITV(6); }
    __builtin_amdgcn_s_barrier();
    COMPA(1, B1);
    MEMCLOB();
    __builtin_amdgcn_s_barrier();
    if (kc + 3 < 16) { LOADB(kc + 3, B1); STAGEH(kc + 3, 1); }
    MEMCLOB();
  }

  // ---------------- epilogue: combine K-halves, write pre/weighted ----------------
  __syncthreads();
  float (*preF)[65] = (float(*)[65])arena;
  if (wk == 1) {
#pragma unroll
    for (int t = 0; t < 4; ++t)
#pragma unroll
      for (int r = 0; r < 4; ++r)
        preF[wm * 16 + lhi * 4 + r][t * 16 + llo] = accA[t][r];
  }
  __syncthreads();
  if (wk == 0) {
#pragma unroll
    for (int t = 0; t < 4; ++t)
#pragma unroll
      for (int r = 0; r < 4; ++r) {
        int row = wm * 16 + lhi * 4 + r;
        float v = accA[t][r] + preF[row][t * 16 + llo] + bias_t[t];
        preRP[row][t * 16 + llo] = f2bf(v);
        wRPT[t * 16 + llo][row] = f2bf(v * sqs_r[r]);
      }
  }
  __syncthreads();

  // ---------------- phase G: per-block partial G ----------------
  {
    f32x4 accG[4];
#pragma unroll
    for (int t = 0; t < 4; ++t) accG[t] = zero4();
    s16x8 ag = *(const s16x8*)&wRPT[wm * 16 + llo][wk * 32 + lhi * 8];
#pragma unroll
    for (int t = 0; t < 4; ++t) {
      s16x8 bg = *(const s16x8*)&wRPT[t * 16 + llo][wk * 32 + lhi * 8];
      accG[t] = __builtin_amdgcn_mfma_f32_16x16x32_bf16(ag, bg, accG[t], 0, 0, 0);
    }
    float* gout = Gpart + ((size_t)blockIdx.x * 2 + wk) * 4096;
#pragma unroll
    for (int t = 0; t < 4; ++t)
#pragma unroll
      for (int r = 0; r < 4; ++r)
        gout[(wm * 16 + lhi * 4 + r) * 64 + t * 16 + llo] = accG[t][r];
  }

  pobL[tid] = pob[tid];
  pobL[tid + 512] = pob[tid + 512];
  __syncthreads();  // drains Gpart stores + pob loads; arena free for MBs

  // ---------------- phase D: pm_read = pre @ M^T + bias ----------------
  const u16* mbb = MB + ((size_t)b << 16);
  const u16* msrc0 = mbb + (size_t)srow * 64 + sc16 * 8;
  auto STAGED = [&](int c, int buf) {
    gload16(msrc0 + (size_t)c * 64 * 64, arena + buf * 16384 + w * 1024);
    gload16(msrc0 + (size_t)(512 + c * 64) * 64, arena + buf * 16384 + 8192 + w * 1024);
  };
  s16x8 ad0 = *(const s16x8*)&preRP[wm * 16 + llo][lhi * 8];
  s16x8 ad1 = *(const s16x8*)&preRP[wm * 16 + llo][32 + lhi * 8];
  float* orow = out + ((size_t)b * N_ + row0 + wm * 16) * D_;

  STAGED(0, 0);
  MEMCLOB();
  STAGED(1, 1);
  MEMCLOB();
  for (int c = 0; c < 8; ++c) {
    if (c == 0) { WAITV(2); }
    else if (c == 7) { WAITV(16); }
    else { WAITV(18); }
    __builtin_amdgcn_s_barrier();
    {
      const char* dbase = arena + (c & 1) * 16384 + wk * 8192;
#pragma unroll
      for (int i = 0; i < 4; ++i) {
        int row = i * 16 + llo;
        int r7 = row & 7;
        const char* base = dbase + row * 128;
        s16x8 b0 = *(const s16x8*)(base + ((lhi ^ r7) * 16));
        s16x8 b1 = *(const s16x8*)(base + (((4 + lhi) ^ r7) * 16));
        f32x4 acc = zero4();
        acc = __builtin_amdgcn_mfma_f32_16x16x32_bf16(ad0, b0, acc, 0, 0, 0);
        acc = __builtin_amdgcn_mfma_f32_16x16x32_bf16(ad1, b1, acc, 0, 0, 0);
        int n0 = wk * 512 + c * 64 + i * 16;
        float bias = pobL[n0 + llo];
#pragma unroll
        for (int r = 0; r < 4; ++r)
          orow[(size_t)(lhi * 4 + r) * D_ + n0 + llo] = acc[r] + bias;
      }
    }
    MEMCLOB();
    __builtin_amdgcn_s_barrier();
    if (c + 2 < 8) STAGED(c + 2, c & 1);
    MEMCLOB();
  }
}

// ---------------- K2: reduce Gpart -> Gsum ----------------
__global__ __launch_bounds__(256) void k_gred(
    const float* __restrict__ Gpart, float* __restrict__ Gsum) {
  __shared__ float red[4][64];
  int b = blockIdx.x >> 6, g = blockIdx.x & 63;
  int lane = threadIdx.x & 63, q = threadIdx.x >> 6;
  const float* src = Gpart + ((size_t)b * 128 + q * 32) * 4096 + g * 64 + lane;
  float s = 0.f;
#pragma unroll 8
  for (int i = 0; i < 32; ++i) s += src[(size_t)i * 4096];
  red[q][lane] = s;
  __syncthreads();
  if (q == 0)
    Gsum[(size_t)b * 4096 + g * 64 + lane] =
        red[0][lane] + red[1][lane] + red[2][lane] + red[3][lane];
}

// ---------------- K3: W_new = W_pm @ (decay*I + beta*G/N), frob clip ----------------
__global__ __launch_bounds__(256) void k_wnew(
    const float* __restrict__ Wpm, const float* __restrict__ Gsum,
    const float* __restrict__ rbeta, const float* __restrict__ rdecay,
    float* __restrict__ outW) {
  __shared__ float Wk[64][66];
  __shared__ float Gl[64][66];
  __shared__ float red[4];
  int bk = blockIdx.x;
  int b = bk >> 3, k = bk & 7;
  int tid = threadIdx.x;
  const float* wsrc = Wpm + (size_t)bk * 4096;
  const float* gsrc = Gsum + (size_t)b * 4096;
  for (int idx = tid; idx < 4096; idx += 256) {
    Wk[idx >> 6][idx & 63] = wsrc[idx];
    Gl[idx >> 6][idx & 63] = gsrc[idx];
  }
  __syncthreads();
  float beta = log1pf(__expf(rbeta[k]));
  float decay = 1.f / (1.f + __expf(-rdecay[k]));
  float bn = beta * (1.f / 4096.f);  // G partials are unnormalized
  int q = tid & 63;
  int rbase = tid >> 6;
  float vals[16];
  float ss = 0.f;
#pragma unroll
  for (int i = 0; i < 16; ++i) {
    int row = i * 4 + rbase;
    float acc = 0.f;
#pragma unroll 8
    for (int j = 0; j < 64; ++j) acc += Wk[row][j] * Gl[j][q];
    float v = decay * Wk[row][q] + bn * acc;
    vals[i] = v;
    ss += v * v;
  }
#pragma unroll
  for (int m = 1; m < 64; m <<= 1) ss += __shfl_xor(ss, m, 64);
  if ((tid & 63) == 0) red[tid >> 6] = ss;
  __syncthreads();
  float frob = sqrtf(red[0] + red[1] + red[2] + red[3]);
  float scale = fminf(16.f / fmaxf(frob, 1e-8f), 1.f);
  float* dst = outW + (size_t)bk * 4096;
#pragma unroll
  for (int i = 0; i < 16; ++i) dst[i * 256 + tid] = vals[i] * scale;
}

extern "C" void kernel_launch(void* const* d_in, const int* in_sizes, int n_in,
                              void* d_out, int out_size, void* d_ws, size_t ws_size,
                              hipStream_t stream) {
  const float* H      = (const float*)d_in[0];
  const float* Sur    = (const float*)d_in[1];
  const float* Wpm    = (const float*)d_in[2];
  const float* piw    = (const float*)d_in[3];
  const float* pib    = (const float*)d_in[4];
  const float* pw     = (const float*)d_in[5];
  const float* pob    = (const float*)d_in[6];
  const float* rbeta  = (const float*)d_in[7];
  const float* rdecay = (const float*)d_in[8];
  const float* sscale = (const float*)d_in[9];
  const float* sbias  = (const float*)d_in[10];
  float* out = (float*)d_out;

  char* ws = (char*)d_ws;
  u16* WpB      = (u16*)(ws);                 // [64][1024] bf16      = 131072 B
  u16* MB       = (u16*)(ws + 131072);        // [8][1024][64] bf16   = 1 MB
  float* sqs_ws = (float*)(ws + 1179648);     // [8][4096] f32        = 131072 B
  float* Gsum   = (float*)(ws + 1310720);     // [8][64][64] f32      = 131072 B
  float* Gpart  = (float*)(ws + 1441792);     // [1024][64][64] f32   = 16 MB

  k_aux<<<2192, 256, 0, stream>>>(Wpm, piw, pw, Sur, sscale, sbias,
                                  WpB, MB, sqs_ws);
  k_main<<<512, 512, 0, stream>>>(H, pib, pob, WpB, MB, sqs_ws, Gpart, out);
  k_gred<<<512, 256, 0, stream>>>(Gpart, Gsum);
  k_wnew<<<64, 256, 0, stream>>>(Wpm, Gsum, rbeta, rdecay,
                                 out + (size_t)8 * 4096 * 1024);
}

// Round 14
// 135.265 us; speedup vs baseline: 1.3436x; 1.0244x over previous
//
#include <hip/hip_runtime.h>

typedef unsigned short u16;
typedef unsigned int u32;
typedef __attribute__((ext_vector_type(4))) float f32x4;
typedef __attribute__((ext_vector_type(8))) short s16x8;

static constexpr int N_ = 4096;
static constexpr int D_ = 1024;

#define WAITV(N) asm volatile("s_waitcnt vmcnt(" #N ")" ::: "memory")
#define MEMCLOB() asm volatile("" ::: "memory")

__device__ __forceinline__ u16 f2bf(float f) {
  unsigned u = __float_as_uint(f);
  u += 0x7FFFu + ((u >> 16) & 1u);  // RNE
  return (u16)(u >> 16);
}
__device__ __forceinline__ float bf2f(u16 v) {
  return __uint_as_float((u32)v << 16);
}
__device__ __forceinline__ f32x4 zero4() {
  f32x4 z; z[0] = 0.f; z[1] = 0.f; z[2] = 0.f; z[3] = 0.f; return z;
}
__device__ __forceinline__ void gload16(const void* g, void* lds) {
  __builtin_amdgcn_global_load_lds(
      (const __attribute__((address_space(1))) u32*)g,
      (__attribute__((address_space(3))) u32*)lds, 16, 0, 0);
}

// ---------------- K0: prep (WpB, MB) + surprise norms ----------------
// blocks 0..15: WpB bf16; 16..143: M = Pow @ Wsum;
// 144..8335: row norms, ONE WAVE PER ROW (4 rows/block).
__global__ __launch_bounds__(256) void k_aux(
    const float* __restrict__ Wpm, const float* __restrict__ piw,
    const float* __restrict__ pw, const float* __restrict__ Sur,
    const float* __restrict__ sscale_p, const float* __restrict__ sbias_p,
    u16* __restrict__ WpB, u16* __restrict__ MB, float* __restrict__ sqs_ws) {
  __shared__ float Ws[64][65];
  int bid = blockIdx.x, tid = threadIdx.x;
  if (bid < 16) {
    size_t i0 = (size_t)bid * 4096;
    for (int idx = tid; idx < 4096; idx += 256)
      WpB[i0 + idx] = f2bf(piw[i0 + idx]);
    return;
  }
  if (bid < 144) {
    int idx2 = bid - 16;
    int b = idx2 >> 4, t = idx2 & 15;
    for (int idx = tid; idx < 4096; idx += 256) {
      float s = 0.f;
#pragma unroll
      for (int k = 0; k < 8; ++k)
        s += Wpm[((size_t)(b * 8 + k)) * 4096 + idx];
      Ws[idx >> 6][idx & 63] = s;
    }
    __syncthreads();
    u16* mb = MB + ((size_t)b << 16);
    for (int oidx = tid; oidx < 4096; oidx += 256) {
      int r = oidx >> 6, c = oidx & 63;
      int drow = t * 64 + r;
      const float* prow = pw + (size_t)drow * 64;
      float acc = 0.f;
#pragma unroll 8
      for (int q = 0; q < 64; ++q) acc += prow[q] * Ws[q][c];
      mb[(size_t)drow * 64 + c] = f2bf(acc);
    }
    return;
  }
  // ---- norms: one wave per row; lane reads 4 coalesced float4 ----
  int w = tid >> 6, lane = tid & 63;
  int grow = (bid - 144) * 4 + w;  // global row in [0, 32768)
  const float4* rp = (const float4*)(Sur + (size_t)grow * D_);
  float4 v0 = rp[lane];
  float4 v1 = rp[lane + 64];
  float4 v2 = rp[lane + 128];
  float4 v3 = rp[lane + 192];
  float a = v0.x * v0.x + v0.y * v0.y + v0.z * v0.z + v0.w * v0.w +
            v1.x * v1.x + v1.y * v1.y + v1.z * v1.z + v1.w * v1.w +
            v2.x * v2.x + v2.y * v2.y + v2.z * v2.z + v2.w * v2.w +
            v3.x * v3.x + v3.y * v3.y + v3.z * v3.z + v3.w * v3.w;
#pragma unroll
  for (int m = 1; m < 64; m <<= 1) a += __shfl_xor(a, m, 64);
  if (lane == 0) {
    float mag = sqrtf(a);
    float s = 1.f / (1.f + __expf(-(sscale_p[0] * mag + sbias_p[0])));
    sqs_ws[grow] = sqrtf(s);
  }
}

// ---------------- K1: fused read/commit main pass (round-4, ~80 us) ----------------
// 512 blocks (8 b x 64 tiles), 512 threads (8 waves). wm=w&3 (16 rows),
// wk=w>>2 (K-half in A / k-rows in G / N-half in D).
__global__ __launch_bounds__(512, 4) void k_main(
    const float* __restrict__ H, const float* __restrict__ pib,
    const float* __restrict__ pob, const u16* __restrict__ WpB,
    const u16* __restrict__ MB, const float* __restrict__ sqs_ws,
    u16* __restrict__ GpartB, float* __restrict__ out) {
  __shared__ __align__(16) char arena[32768];  // Hs/MBs[2 buf][2 slab][8192] | preF
  __shared__ __align__(16) u16 preRP[64][72];
  __shared__ __align__(16) u16 wRPT[64][72];
  __shared__ float pobL[1024];

  const int tid = threadIdx.x;
  const int lane = tid & 63;
  const int w = tid >> 6;
  const int wm = w & 3;
  const int wk = w >> 2;
  const int llo = lane & 15;
  const int lhi = lane >> 4;
  const int b = blockIdx.x >> 6;
  const int row0 = (blockIdx.x & 63) * 64;

  // small operands into regs early (latency fully hidden)
  float bias_t[4];
#pragma unroll
  for (int t = 0; t < 4; ++t) bias_t[t] = pib[t * 16 + llo];
  float sqs_r[4];
#pragma unroll
  for (int r = 0; r < 4; ++r)
    sqs_r[r] = sqs_ws[b * 4096 + row0 + wm * 16 + lhi * 4 + r];

  // staging lane params (shared by phase A and D)
  const int srow = 8 * w + (lane >> 3);
  const int sc16 = (lane & 7) ^ (srow & 7);

  // ---------------- phase A: pre = H @ Wp^T ----------------
  f32x4 accA[4];
#pragma unroll
  for (int t = 0; t < 4; ++t) accA[t] = zero4();

  const float* hsrc = H + ((size_t)b * N_ + row0 + srow) * D_ + sc16 * 4;
  const u16* wpb = WpB + (size_t)wk * 512 + lhi * 8;

  s16x8 B0[4], B1[4];
  auto LOADB = [&](int kc, s16x8* Bs) {
#pragma unroll
    for (int t = 0; t < 4; ++t)
      Bs[t] = *(const s16x8*)(wpb + (size_t)(t * 16 + llo) * 1024 + kc * 32);
  };
  auto STAGEH = [&](int kc, int buf) {
    gload16(hsrc + kc * 32, arena + buf * 16384 + w * 1024);
    gload16(hsrc + 512 + kc * 32, arena + buf * 16384 + 8192 + w * 1024);
  };
  const int arow = wm * 16 + llo;
  const int r7a = arow & 7;
  auto COMPA = [&](int buf, const s16x8* Bs) {
    const char* abase = arena + buf * 16384 + wk * 8192 + arow * 128;
    f32x4 alo = *(const f32x4*)(abase + (((lhi * 2) ^ r7a) * 16));
    f32x4 ahi = *(const f32x4*)(abase + (((lhi * 2 + 1) ^ r7a) * 16));
    s16x8 af;
    af[0] = (short)f2bf(alo[0]); af[1] = (short)f2bf(alo[1]);
    af[2] = (short)f2bf(alo[2]); af[3] = (short)f2bf(alo[3]);
    af[4] = (short)f2bf(ahi[0]); af[5] = (short)f2bf(ahi[1]);
    af[6] = (short)f2bf(ahi[2]); af[7] = (short)f2bf(ahi[3]);
#pragma unroll
    for (int t = 0; t < 4; ++t)
      accA[t] = __builtin_amdgcn_mfma_f32_16x16x32_bf16(af, Bs[t], accA[t], 0, 0, 0);
  };

  LOADB(0, B0); STAGEH(0, 0);
  MEMCLOB();
  LOADB(1, B1); STAGEH(1, 1);
  MEMCLOB();

  for (int kc = 0; kc < 16; kc += 2) {
    WAITV(6);
    __builtin_amdgcn_s_barrier();
    COMPA(0, B0);
    MEMCLOB();
    __builtin_amdgcn_s_barrier();
    if (kc + 2 < 16) { LOADB(kc + 2, B0); STAGEH(kc + 2, 0); }
    MEMCLOB();
    if (kc + 1 == 15) { WAITV(0); } else { WAITV(6); }
    __builtin_amdgcn_s_barrier();
    COMPA(1, B1);
    MEMCLOB();
    __builtin_amdgcn_s_barrier();
    if (kc + 3 < 16) { LOADB(kc + 3, B1); STAGEH(kc + 3, 1); }
    MEMCLOB();
  }

  // ---------------- epilogue: combine K-halves, write pre/weighted ----------------
  __syncthreads();
  float (*preF)[65] = (float(*)[65])arena;
  if (wk == 1) {
#pragma unroll
    for (int t = 0; t < 4; ++t)
#pragma unroll
      for (int r = 0; r < 4; ++r)
        preF[wm * 16 + lhi * 4 + r][t * 16 + llo] = accA[t][r];
  }
  __syncthreads();
  if (wk == 0) {
#pragma unroll
    for (int t = 0; t < 4; ++t)
#pragma unroll
      for (int r = 0; r < 4; ++r) {
        int row = wm * 16 + lhi * 4 + r;
        float v = accA[t][r] + preF[row][t * 16 + llo] + bias_t[t];
        preRP[row][t * 16 + llo] = f2bf(v);
        wRPT[t * 16 + llo][row] = f2bf(v * sqs_r[r]);
      }
  }
  __syncthreads();

  // ---------------- phase G: per-block partial G (bf16 out) ----------------
  {
    f32x4 accG[4];
#pragma unroll
    for (int t = 0; t < 4; ++t) accG[t] = zero4();
    s16x8 ag = *(const s16x8*)&wRPT[wm * 16 + llo][wk * 32 + lhi * 8];
#pragma unroll
    for (int t = 0; t < 4; ++t) {
      s16x8 bg = *(const s16x8*)&wRPT[t * 16 + llo][wk * 32 + lhi * 8];
      accG[t] = __builtin_amdgcn_mfma_f32_16x16x32_bf16(ag, bg, accG[t], 0, 0, 0);
    }
    u16* gout = GpartB + ((size_t)blockIdx.x * 2 + wk) * 4096;
#pragma unroll
    for (int t = 0; t < 4; ++t)
#pragma unroll
      for (int r = 0; r < 4; ++r)
        gout[(wm * 16 + lhi * 4 + r) * 64 + t * 16 + llo] = f2bf(accG[t][r]);
  }

  pobL[tid] = pob[tid];
  pobL[tid + 512] = pob[tid + 512];
  __syncthreads();  // drains GpartB stores + pob loads; arena free for MBs

  // ---------------- phase D: pm_read = pre @ M^T + bias ----------------
  const u16* mbb = MB + ((size_t)b << 16);
  const u16* msrc0 = mbb + (size_t)srow * 64 + sc16 * 8;
  auto STAGED = [&](int c, int buf) {
    gload16(msrc0 + (size_t)c * 64 * 64, arena + buf * 16384 + w * 1024);
    gload16(msrc0 + (size_t)(512 + c * 64) * 64, arena + buf * 16384 + 8192 + w * 1024);
  };
  s16x8 ad0 = *(const s16x8*)&preRP[wm * 16 + llo][lhi * 8];
  s16x8 ad1 = *(const s16x8*)&preRP[wm * 16 + llo][32 + lhi * 8];
  float* orow = out + ((size_t)b * N_ + row0 + wm * 16) * D_;

  STAGED(0, 0);
  MEMCLOB();
  STAGED(1, 1);
  MEMCLOB();
  for (int c = 0; c < 8; ++c) {
    if (c == 0) { WAITV(2); }
    else if (c == 7) { WAITV(16); }
    else { WAITV(18); }
    __builtin_amdgcn_s_barrier();
    {
      const char* dbase = arena + (c & 1) * 16384 + wk * 8192;
#pragma unroll
      for (int i = 0; i < 4; ++i) {
        int row = i * 16 + llo;
        int r7 = row & 7;
        const char* base = dbase + row * 128;
        s16x8 b0 = *(const s16x8*)(base + ((lhi ^ r7) * 16));
        s16x8 b1 = *(const s16x8*)(base + (((4 + lhi) ^ r7) * 16));
        f32x4 acc = zero4();
        acc = __builtin_amdgcn_mfma_f32_16x16x32_bf16(ad0, b0, acc, 0, 0, 0);
        acc = __builtin_amdgcn_mfma_f32_16x16x32_bf16(ad1, b1, acc, 0, 0, 0);
        int n0 = wk * 512 + c * 64 + i * 16;
        float bias = pobL[n0 + llo];
#pragma unroll
        for (int r = 0; r < 4; ++r)
          orow[(size_t)(lhi * 4 + r) * D_ + n0 + llo] = acc[r] + bias;
      }
    }
    MEMCLOB();
    __builtin_amdgcn_s_barrier();
    if (c + 2 < 8) STAGED(c + 2, c & 1);
    MEMCLOB();
  }
}

// ---------------- K2: reduce GpartB (bf16) -> Gsum (f32) ----------------
__global__ __launch_bounds__(256) void k_gred(
    const u16* __restrict__ GpartB, float* __restrict__ Gsum) {
  __shared__ float red[4][64];
  int b = blockIdx.x >> 6, g = blockIdx.x & 63;
  int lane = threadIdx.x & 63, q = threadIdx.x >> 6;
  const u16* src = GpartB + ((size_t)(b * 128 + q * 32)) * 4096 + g * 64 + lane;
  float s = 0.f;
#pragma unroll 8
  for (int i = 0; i < 32; ++i) s += bf2f(src[(size_t)i * 4096]);
  red[q][lane] = s;
  __syncthreads();
  if (q == 0)
    Gsum[(size_t)b * 4096 + g * 64 + lane] =
        red[0][lane] + red[1][lane] + red[2][lane] + red[3][lane];
}

// ---------------- K3: W_new = W_pm @ (decay*I + beta*G/N), frob clip ----------------
__global__ __launch_bounds__(256) void k_wnew(
    const float* __restrict__ Wpm, const float* __restrict__ Gsum,
    const float* __restrict__ rbeta, const float* __restrict__ rdecay,
    float* __restrict__ outW) {
  __shared__ float Wk[64][66];
  __shared__ float Gl[64][66];
  __shared__ float red[4];
  int bk = blockIdx.x;
  int b = bk >> 3, k = bk & 7;
  int tid = threadIdx.x;
  const float* wsrc = Wpm + (size_t)bk * 4096;
  const float* gsrc = Gsum + (size_t)b * 4096;
  for (int idx = tid; idx < 4096; idx += 256) {
    Wk[idx >> 6][idx & 63] = wsrc[idx];
    Gl[idx >> 6][idx & 63] = gsrc[idx];
  }
  __syncthreads();
  float beta = log1pf(__expf(rbeta[k]));
  float decay = 1.f / (1.f + __expf(-rdecay[k]));
  float bn = beta * (1.f / 4096.f);  // G partials are unnormalized
  int q = tid & 63;
  int rbase = tid >> 6;
  float vals[16];
  float ss = 0.f;
#pragma unroll
  for (int i = 0; i < 16; ++i) {
    int row = i * 4 + rbase;
    float acc = 0.f;
#pragma unroll 8
    for (int j = 0; j < 64; ++j) acc += Wk[row][j] * Gl[j][q];
    float v = decay * Wk[row][q] + bn * acc;
    vals[i] = v;
    ss += v * v;
  }
#pragma unroll
  for (int m = 1; m < 64; m <<= 1) ss += __shfl_xor(ss, m, 64);
  if ((tid & 63) == 0) red[tid >> 6] = ss;
  __syncthreads();
  float frob = sqrtf(red[0] + red[1] + red[2] + red[3]);
  float scale = fminf(16.f / fmaxf(frob, 1e-8f), 1.f);
  float* dst = outW + (size_t)bk * 4096;
#pragma unroll
  for (int i = 0; i < 16; ++i) dst[i * 256 + tid] = vals[i] * scale;
}

extern "C" void kernel_launch(void* const* d_in, const int* in_sizes, int n_in,
                              void* d_out, int out_size, void* d_ws, size_t ws_size,
                              hipStream_t stream) {
  const float* H      = (const float*)d_in[0];
  const float* Sur    = (const float*)d_in[1];
  const float* Wpm    = (const float*)d_in[2];
  const float* piw    = (const float*)d_in[3];
  const float* pib    = (const float*)d_in[4];
  const float* pw     = (const float*)d_in[5];
  const float* pob    = (const float*)d_in[6];
  const float* rbeta  = (const float*)d_in[7];
  const float* rdecay = (const float*)d_in[8];
  const float* sscale = (const float*)d_in[9];
  const float* sbias  = (const float*)d_in[10];
  float* out = (float*)d_out;

  char* ws = (char*)d_ws;
  u16* WpB      = (u16*)(ws);                 // [64][1024] bf16      = 131072 B
  u16* MB       = (u16*)(ws + 131072);        // [8][1024][64] bf16   = 1 MB
  float* sqs_ws = (float*)(ws + 1179648);     // [8][4096] f32        = 131072 B
  float* Gsum   = (float*)(ws + 1310720);     // [8][64][64] f32      = 131072 B
  u16* GpartB   = (u16*)(ws + 1441792);       // [1024][64][64] bf16  = 8 MB

  k_aux<<<8336, 256, 0, stream>>>(Wpm, piw, pw, Sur, sscale, sbias,
                                  WpB, MB, sqs_ws);
  k_main<<<512, 512, 0, stream>>>(H, pib, pob, WpB, MB, sqs_ws, GpartB, out);
  k_gred<<<512, 256, 0, stream>>>(GpartB, Gsum);
  k_wnew<<<64, 256, 0, stream>>>(Wpm, Gsum, rbeta, rdecay,
                                 out + (size_t)8 * 4096 * 1024);
}